// Round 15
// baseline (287.971 us; speedup 1.0000x reference)
//
#include <hip/hip_runtime.h>
#include <hip/hip_bf16.h>

#define NHEADS 4
#define DIM 128
#define NEG_SLOPE 0.2f
#define POOL_CHUNK 256

typedef __bf16 bf16x8 __attribute__((ext_vector_type(8)));
typedef float  f32x4  __attribute__((ext_vector_type(4)));

__device__ __forceinline__ float lrelu(float x) { return x > 0.f ? x : NEG_SLOPE * x; }
__device__ __forceinline__ float bf2f(unsigned short u) {
    return __uint_as_float(((unsigned)u) << 16);
}
__device__ __forceinline__ unsigned short f2bf(float f) {
    __bf16 b = (__bf16)f;
    return __builtin_bit_cast(unsigned short, b);
}
__device__ __forceinline__ unsigned pack2bf(float a, float b) {
    return (unsigned)f2bf(a) | ((unsigned)f2bf(b) << 16);
}
__device__ __forceinline__ float4 lrelu4(float4 a, float4 b) {
    return make_float4(lrelu(a.x + b.x), lrelu(a.y + b.y), lrelu(a.z + b.z), lrelu(a.w + b.w));
}
__device__ __forceinline__ float4 redsum4(float4 v) {
#pragma unroll
    for (int off = 32; off >= 1; off >>= 1) {
        v.x += __shfl_xor(v.x, off);
        v.y += __shfl_xor(v.y, off);
        v.z += __shfl_xor(v.z, off);
        v.w += __shfl_xor(v.w, off);
    }
    return v;
}

// ---------------- one-dispatch zero of deg + pooled ----------------
__global__ __launch_bounds__(256) void zero_bufs(
    int* __restrict__ deg, int n, float* __restrict__ pooled, int pn)
{
    int i = blockIdx.x * 256 + threadIdx.x;
    int stride = gridDim.x * 256;
    for (int k = i; k < n; k += stride) deg[k] = 0;
    for (int k = i; k < pn; k += stride) pooled[k] = 0.f;
}

// ---------------- bf16-MFMA GEMM body + fused attention coefficients ----------------
template<bool ABF>
__device__ __forceinline__ void gemm_body(
    const float* __restrict__ inF, const unsigned short* __restrict__ inB,
    const uint4* __restrict__ Wb4, const float* __restrict__ bias,
    const float* __restrict__ attl, const float* __restrict__ attr,
    __bf16* __restrict__ xlb, float* __restrict__ al, float* __restrict__ ar,
    int n, int bid)
{
    const int tid = threadIdx.x;
    const int wid = tid >> 6, l = tid & 63;
    const int rowA = bid * 64 + wid * 16 + (l & 15);
    const int kchunk = (l >> 4) * 8;

    f32x4 acc[8];
#pragma unroll
    for (int g = 0; g < 8; ++g)
#pragma unroll
        for (int r = 0; r < 4; ++r) acc[g][r] = 0.f;

#pragma unroll
    for (int kk = 0; kk < 4; ++kk) {
        bf16x8 afrag;
        if (ABF) {
            uint4 u = make_uint4(0, 0, 0, 0);
            if (rowA < n)
                u = *(const uint4*)(inB + (size_t)rowA * DIM + kk * 32 + kchunk);
            afrag = __builtin_bit_cast(bf16x8, u);
        } else {
            float av[8];
            if (rowA < n) {
                const float* p = inF + (size_t)rowA * DIM + kk * 32 + kchunk;
                float4 x0 = *(const float4*)p;
                float4 x1 = *(const float4*)(p + 4);
                av[0]=x0.x; av[1]=x0.y; av[2]=x0.z; av[3]=x0.w;
                av[4]=x1.x; av[5]=x1.y; av[6]=x1.z; av[7]=x1.w;
            } else {
#pragma unroll
                for (int i = 0; i < 8; ++i) av[i] = 0.f;
            }
#pragma unroll
            for (int i = 0; i < 8; ++i) afrag[i] = (__bf16)av[i];
        }
#pragma unroll
        for (int g = 0; g < 8; ++g) {
            uint4 u = Wb4[(g * 4 + kk) * 64 + l];
            bf16x8 bfrag = __builtin_bit_cast(bf16x8, u);
            acc[g] = __builtin_amdgcn_mfma_f32_16x16x32_bf16(afrag, bfrag, acc[g], 0, 0, 0);
        }
    }

    const int rowbase = bid * 64 + wid * 16 + (l >> 4) * 4;
    float pl[4][4], pr2[4][4];
#pragma unroll
    for (int r = 0; r < 4; ++r)
#pragma unroll
        for (int h = 0; h < 4; ++h) { pl[r][h] = 0.f; pr2[r][h] = 0.f; }

#pragma unroll
    for (int g = 0; g < 8; ++g) {
        int col = g * 16 + (l & 15);
        float bg = bias[col], alg = attl[col], arg = attr[col];
        int h = g >> 1;
#pragma unroll
        for (int r = 0; r < 4; ++r) {
            float v = acc[g][r] + bg;
            int row = rowbase + r;
            if (row < n) xlb[(size_t)row * DIM + col] = (__bf16)v;
            pl[r][h]  = fmaf(v, alg, pl[r][h]);
            pr2[r][h] = fmaf(v, arg, pr2[r][h]);
        }
    }
#pragma unroll
    for (int off = 1; off <= 8; off <<= 1) {
#pragma unroll
        for (int r = 0; r < 4; ++r)
#pragma unroll
            for (int h = 0; h < 4; ++h) {
                pl[r][h]  += __shfl_xor(pl[r][h], off);
                pr2[r][h] += __shfl_xor(pr2[r][h], off);
            }
    }
    if ((l & 15) == 0) {
#pragma unroll
        for (int r = 0; r < 4; ++r) {
            int row = rowbase + r;
            if (row < n) {
#pragma unroll
                for (int h = 0; h < 4; ++h) {
                    al[row * 4 + h] = pl[r][h];
                    ar[row * 4 + h] = pr2[r][h];
                }
            }
        }
    }
}

template<bool ABF>
__global__ __launch_bounds__(256) void gemm_mfma(
    const float* __restrict__ inF, const unsigned short* __restrict__ inB,
    const uint4* __restrict__ Wb4, const float* __restrict__ bias,
    const float* __restrict__ attl, const float* __restrict__ attr,
    __bf16* __restrict__ xlb, float* __restrict__ al, float* __restrict__ ar, int n)
{
    gemm_body<ABF>(inF, inB, Wb4, bias, attl, attr, xlb, al, ar, n, blockIdx.x);
}

// ---- merged: layer-0 GEMM (blocks < gemmBlocks) + LDS-classified edge bucketing ----
__global__ __launch_bounds__(256) void gemm0_classify(
    const float* __restrict__ inF, const uint4* __restrict__ Wb4,
    const float* __restrict__ bias,
    const float* __restrict__ attl, const float* __restrict__ attr,
    __bf16* __restrict__ xlb, float* __restrict__ al, float* __restrict__ ar,
    int n, int gemmBlocks,
    const int* __restrict__ src, const int* __restrict__ dst,
    int* __restrict__ bwpos, unsigned* __restrict__ ebuf, int E)
{
    if ((int)blockIdx.x < gemmBlocks) {
        gemm_body<false>(inF, nullptr, Wb4, bias, attl, attr, xlb, al, ar, n, blockIdx.x);
    } else {
        __shared__ unsigned stage[4096];
        __shared__ unsigned char sid[4096];
        __shared__ int hist[256], lofs[256], wofs[256], gbase[256];
        int t = threadIdx.x;
        int e0 = (blockIdx.x - gemmBlocks) * 4096;
        int cnt = min(4096, E - e0);
        if (cnt <= 0) return;
        hist[t] = 0;
        __syncthreads();
        for (int k = t; k < cnt; k += 256)
            atomicAdd(&hist[dst[e0 + k] >> 8], 1);
        __syncthreads();
        int v = hist[t];
        lofs[t] = v;
        __syncthreads();
        int val = v;
        for (int off = 1; off < 256; off <<= 1) {
            int other = (t >= off) ? lofs[t - off] : 0;
            __syncthreads();
            val += other;
            lofs[t] = val;
            __syncthreads();
        }
        int excl = val - v;
        int gb_ = (v > 0) ? atomicAdd(&bwpos[t], v) : 0;
        lofs[t] = excl; wofs[t] = excl; gbase[t] = gb_;
        __syncthreads();
        for (int k = t; k < cnt; k += 256) {
            int d = dst[e0 + k], s = src[e0 + k];
            int b = d >> 8;
            int slot = atomicAdd(&wofs[b], 1);
            stage[slot] = (unsigned)(s & 0xffff) | ((unsigned)(d & 255) << 16);
            sid[slot] = (unsigned char)b;
        }
        __syncthreads();
        for (int s_ = t; s_ < cnt; s_ += 256) {
            int b = sid[s_];
            ebuf[gbase[b] + (s_ - lofs[b])] = stage[s_];
        }
    }
}

// ---- pass 2: rank within bucket (256 nodes) via LDS counters ----
__global__ __launch_bounds__(256) void bucket_rank(
    const unsigned* __restrict__ ebuf, const int* __restrict__ rowptr,
    int* __restrict__ col, int n)
{
    __shared__ int wp[256];
    int nb0 = blockIdx.x << 8;
    int t = threadIdx.x;
    int nend = min(nb0 + 256, n);
    int base = rowptr[nb0];
    int eend = rowptr[nend];
    if (nb0 + t < nend) wp[t] = rowptr[nb0 + t] - base;
    __syncthreads();
    for (int e = base + t; e < eend; e += 256) {
        unsigned ed = ebuf[e];
        int r = atomicAdd(&wp[(ed >> 16) & 255], 1);
        col[base + r] = (int)(ed & 0xffffu);
    }
}

// ---------------- merged prep: W pack (blocks < wb) + degree count ----------------
__global__ __launch_bounds__(256) void prep_pack_deg(
    const float* __restrict__ Ws, __bf16* __restrict__ Wb, int wtot, int wb,
    const int* __restrict__ dst, int* __restrict__ deg, int E)
{
    if ((int)blockIdx.x < wb) {
        int o = blockIdx.x * 256 + threadIdx.x;
        if (o >= wtot) return;
        int layer = o >> 14;
        int t = o & 16383;
        int j = t & 7, l = (t >> 3) & 63, kk = (t >> 9) & 3, g = t >> 11;
        int col = g * 16 + (l & 15);
        int k = kk * 32 + (l >> 4) * 8 + j;
        Wb[o] = (__bf16)Ws[(size_t)layer * 16384 + col * 128 + k];
    } else {
        int e = (blockIdx.x - wb) * 256 + threadIdx.x;
        if (e < E) atomicAdd(&deg[dst[e]], 1);
    }
}

__global__ __launch_bounds__(256) void scan_blocks(
    const int* __restrict__ deg, int* __restrict__ rowptr,
    int* __restrict__ partials, int n)
{
    __shared__ int tot[256];
    int t = threadIdx.x;
    int base = blockIdx.x * 1024 + t * 4;
    int v[4];
#pragma unroll
    for (int j = 0; j < 4; ++j) v[j] = (base + j < n) ? deg[base + j] : 0;
    int p1 = v[0], p2 = p1 + v[1], p3 = p2 + v[2], sum4 = p3 + v[3];
    tot[t] = sum4;
    __syncthreads();
    int val = sum4;
    for (int off = 1; off < 256; off <<= 1) {
        int other = (t >= off) ? tot[t - off] : 0;
        __syncthreads();
        val += other;
        tot[t] = val;
        __syncthreads();
    }
    int excl = val - sum4;
    if (base < n)     rowptr[base]     = excl;
    if (base+1 < n)   rowptr[base+1]   = excl + p1;
    if (base+2 < n)   rowptr[base+2]   = excl + p2;
    if (base+3 < n)   rowptr[base+3]   = excl + p3;
    if (t == 255) partials[blockIdx.x] = val;
}

__global__ __launch_bounds__(256) void scan_partials(
    int* __restrict__ partials, int nb, int* __restrict__ rowptr, int n)
{
    __shared__ int tot[256];
    int t = threadIdx.x;
    int v = (t < nb) ? partials[t] : 0;
    tot[t] = v;
    __syncthreads();
    int val = v;
    for (int off = 1; off < 256; off <<= 1) {
        int other = (t >= off) ? tot[t - off] : 0;
        __syncthreads();
        val += other;
        tot[t] = val;
        __syncthreads();
    }
    if (t < nb) partials[t] = val - v;
    if (t == 255) rowptr[n] = val;
}

// also seeds bwpos[b] = rowptr[b*256]
__global__ __launch_bounds__(256) void add_offsets(
    int* __restrict__ rowptr, int* __restrict__ bwpos,
    const int* __restrict__ partials, int n)
{
    int base = blockIdx.x * 1024 + threadIdx.x * 4;
    int off = partials[blockIdx.x];
#pragma unroll
    for (int j = 0; j < 4; ++j) {
        int i = base + j;
        if (i < n) {
            int r = rowptr[i] + off;
            rowptr[i] = r;
            if ((i & 255) == 0) bwpos[i >> 8] = r;
        }
    }
}

// ---- accumulate one edge (uint4 = 8 bf16 ch) into a pair of f32x4 ----
__device__ __forceinline__ void acc_edge(
    uint4 v, float w, f32x4& lo, f32x4& hi)
{
    lo[0] = fmaf(w, __uint_as_float(v.x << 16), lo[0]);
    lo[1] = fmaf(w, __uint_as_float(v.x & 0xffff0000u), lo[1]);
    lo[2] = fmaf(w, __uint_as_float(v.y << 16), lo[2]);
    lo[3] = fmaf(w, __uint_as_float(v.y & 0xffff0000u), lo[3]);
    hi[0] = fmaf(w, __uint_as_float(v.z << 16), hi[0]);
    hi[1] = fmaf(w, __uint_as_float(v.z & 0xffff0000u), hi[1]);
    hi[2] = fmaf(w, __uint_as_float(v.w << 16), hi[2]);
    hi[3] = fmaf(w, __uint_as_float(v.w & 0xffff0000u), hi[3]);
}

// chunk of <=64 staged edges; 4 edges/wave-inst (16 lanes x 8ch, uint4 loads),
// 2 unroll groups -> 8 edges in flight (R11 proven form). Tail: FULL guarded loop.
__device__ __forceinline__ void agg_chunk4w(
    const int* __restrict__ slds, const float* __restrict__ wl,
    int cn, int eg, const unsigned short* __restrict__ xp,
    f32x4& A0, f32x4& A1, f32x4& B0, f32x4& B1)
{
    int i = 0;
    for (; i + 8 <= cn; i += 8) {
        int e0 = i + eg, e1 = i + 4 + eg;
        int s0 = slds[e0], s1 = slds[e1];
        float w0 = wl[e0*4], w1 = wl[e1*4];
        uint4 v0 = *(const uint4*)(xp + (size_t)s0 * DIM);
        uint4 v1 = *(const uint4*)(xp + (size_t)s1 * DIM);
        acc_edge(v0, w0, A0, A1);
        acc_edge(v1, w1, B0, B1);
    }
    for (; i < cn; i += 4) {
        int e = i + eg;
        if (e < cn) {
            int s = slds[e];
            float w = wl[e*4];
            uint4 v = *(const uint4*)(xp + (size_t)s * DIM);
            acc_edge(v, w, A0, A1);
        }
    }
}

// ---------------- fused per-node softmax + aggregate (bf16 gather) ----------
// PERSISTENT grid-stride over nodes: 12500 short 4-wave blocks caused dispatch
// churn (occupancy ~45% despite static limits allowing ~100%). 8 blocks/CU
// loop over nodes; no barriers in the body so per-wave looping is safe.
__global__ __launch_bounds__(256) void gat_aggregate(
    const int* __restrict__ rowptr, const int* __restrict__ col,
    const float* __restrict__ al, const float* __restrict__ ar,
    const unsigned short* __restrict__ xlb, unsigned short* __restrict__ outb, int n)
{
    __shared__ float4 wlds[4][64];
    __shared__ int    slds[4][64];
    int wid = threadIdx.x >> 6;
    int lane = threadIdx.x & 63;
    int eg = lane >> 4, c16 = lane & 15;
    int h = c16 >> 2;
    const float* wl = (const float*)&wlds[wid][0] + h;
    const unsigned short* xp = xlb + c16 * 8;
    const int nstride = gridDim.x * 4;

    for (int node = blockIdx.x * 4 + wid; node < n; node += nstride) {
        int r0 = rowptr[node], r1 = rowptr[node + 1];
        int deg = r1 - r0;
        unsigned short* po = outb + (size_t)node * DIM + c16 * 8;
        if (deg == 0) {
            if (eg == 0) *(uint4*)po = make_uint4(0, 0, 0, 0);
            continue;
        }

        float4 arv = *(const float4*)(ar + (size_t)node * 4);
        f32x4 A0 = {0,0,0,0}, A1 = {0,0,0,0}, B0 = {0,0,0,0}, B1 = {0,0,0,0};
        float4 inv4;

        if (deg <= 64) {
            float4 p4 = make_float4(0.f, 0.f, 0.f, 0.f);
            int s = 0;
            if (lane < deg) {
                s = col[r0 + lane];
                float4 a = *(const float4*)(al + (size_t)s * 4);
                float4 l4 = lrelu4(arv, a);
                p4.x = __expf(l4.x); p4.y = __expf(l4.y);
                p4.z = __expf(l4.z); p4.w = __expf(l4.w);
            }
            float4 s4 = redsum4(p4);
            inv4 = make_float4(1.f/(s4.x+1e-16f), 1.f/(s4.y+1e-16f),
                               1.f/(s4.z+1e-16f), 1.f/(s4.w+1e-16f));
            if (lane < deg) { wlds[wid][lane] = p4; slds[wid][lane] = s; }
            __asm__ volatile("s_waitcnt lgkmcnt(0)" ::: "memory");
            __builtin_amdgcn_sched_barrier(0);
            agg_chunk4w(&slds[wid][0], wl, deg, eg, xp, A0, A1, B0, B1);
            __asm__ volatile("s_waitcnt lgkmcnt(0)" ::: "memory");
            __builtin_amdgcn_sched_barrier(0);
        } else {
            float4 s4 = make_float4(0.f, 0.f, 0.f, 0.f);
            for (int i = lane; i < deg; i += 64) {
                int s = col[r0 + i];
                float4 a = *(const float4*)(al + (size_t)s * 4);
                float4 t = lrelu4(arv, a);
                s4.x += __expf(t.x); s4.y += __expf(t.y);
                s4.z += __expf(t.z); s4.w += __expf(t.w);
            }
            s4 = redsum4(s4);
            inv4 = make_float4(1.f/(s4.x+1e-16f), 1.f/(s4.y+1e-16f),
                               1.f/(s4.z+1e-16f), 1.f/(s4.w+1e-16f));
            for (int c0 = 0; c0 < deg; c0 += 64) {
                int cn = min(64, deg - c0);
                if (lane < cn) {
                    int s = col[r0 + c0 + lane];
                    float4 a = *(const float4*)(al + (size_t)s * 4);
                    float4 t = lrelu4(arv, a);
                    float4 p;
                    p.x = __expf(t.x); p.y = __expf(t.y);
                    p.z = __expf(t.z); p.w = __expf(t.w);
                    wlds[wid][lane] = p; slds[wid][lane] = s;
                }
                __asm__ volatile("s_waitcnt lgkmcnt(0)" ::: "memory");
                __builtin_amdgcn_sched_barrier(0);
                agg_chunk4w(&slds[wid][0], wl, cn, eg, xp, A0, A1, B0, B1);
                __asm__ volatile("s_waitcnt lgkmcnt(0)" ::: "memory");
                __builtin_amdgcn_sched_barrier(0);
            }
        }
        float invh = (h == 0) ? inv4.x : (h == 1) ? inv4.y : (h == 2) ? inv4.z : inv4.w;
#pragma unroll
        for (int j = 0; j < 4; ++j) {
            A0[j] += B0[j];
            A1[j] += B1[j];
            A0[j] += __shfl_xor(A0[j], 16); A0[j] += __shfl_xor(A0[j], 32);
            A1[j] += __shfl_xor(A1[j], 16); A1[j] += __shfl_xor(A1[j], 32);
        }
        if (eg == 0) {
            uint4 o4;
            o4.x = pack2bf(fmaxf(A0[0]*invh, 0.f), fmaxf(A0[1]*invh, 0.f));
            o4.y = pack2bf(fmaxf(A0[2]*invh, 0.f), fmaxf(A0[3]*invh, 0.f));
            o4.z = pack2bf(fmaxf(A1[0]*invh, 0.f), fmaxf(A1[1]*invh, 0.f));
            o4.w = pack2bf(fmaxf(A1[2]*invh, 0.f), fmaxf(A1[3]*invh, 0.f));
            *(uint4*)po = o4;
        }
    }
}

// ---------------- graph pooling: segmented (batch sorted); h relu'd bf16 ----
__global__ __launch_bounds__(256) void pool_nodes_seg(
    const unsigned short* __restrict__ h, const int* __restrict__ batch,
    float* __restrict__ pooled, int n)
{
    int wid = threadIdx.x >> 6;
    int lane = threadIdx.x & 63;
    int start = blockIdx.x * POOL_CHUNK;
    int end = min(start + POOL_CHUNK, n);
    float a0 = 0.f, a1 = 0.f;
    int curg = -1;
    for (int node = start + wid; node < end; node += 4) {
        int g = batch[node];
        if (g != curg) {
            if (curg >= 0) {
                unsafeAtomicAdd(pooled + (size_t)curg * DIM + lane*2,     a0);
                unsafeAtomicAdd(pooled + (size_t)curg * DIM + lane*2 + 1, a1);
            }
            curg = g; a0 = 0.f; a1 = 0.f;
        }
        ushort2 v = *(const ushort2*)(h + (size_t)node * DIM + lane * 2);
        a0 += bf2f(v.x);
        a1 += bf2f(v.y);
    }
    if (curg >= 0) {
        unsafeAtomicAdd(pooled + (size_t)curg * DIM + lane*2,     a0);
        unsafeAtomicAdd(pooled + (size_t)curg * DIM + lane*2 + 1, a1);
    }
}

// ---------------- final projection ----------------
__global__ __launch_bounds__(256) void proj_out(
    const float* __restrict__ pooled, const float* __restrict__ W,
    const float* __restrict__ b, float* __restrict__ out, int G)
{
    int idx = blockIdx.x * blockDim.x + threadIdx.x;
    if (idx >= G * 32) return;
    int g = idx >> 5, j = idx & 31;
    const float* pr = pooled + (size_t)g * DIM;
    const float* wr = W + (size_t)j * DIM;
    float acc = 0.f;
#pragma unroll
    for (int k = 0; k < DIM; ++k) acc = fmaf(pr[k], wr[k], acc);
    out[idx] = acc + b[j];
}

extern "C" void kernel_launch(void* const* d_in, const int* in_sizes, int n_in,
                              void* d_out, int out_size, void* d_ws, size_t ws_size,
                              hipStream_t stream)
{
    const float* x      = (const float*)d_in[0];
    const int*   eidx   = (const int*)d_in[1];
    const int*   batch  = (const int*)d_in[2];
    const float* Ws     = (const float*)d_in[3];
    const float* bs     = (const float*)d_in[4];
    const float* attls  = (const float*)d_in[5];
    const float* attrs  = (const float*)d_in[6];
    const float* projW  = (const float*)d_in[7];
    const float* projb  = (const float*)d_in[8];

    const int N = in_sizes[0] / DIM;
    const int E = in_sizes[1] / 2;
    const int G = out_size / 32;
    const int* src = eidx;
    const int* dst = eidx + E;

    char* ws = (char*)d_ws;
    size_t o = 0;
    auto alloc = [&](size_t bytes) { char* p = ws + o; o += (bytes + 255) & ~255ull; return p; };
    unsigned short* hA  = (unsigned short*)alloc((size_t)N * DIM * 2);
    unsigned short* hB  = (unsigned short*)alloc((size_t)N * DIM * 2);
    __bf16* xlb    = (__bf16*)alloc((size_t)N * DIM * 2);
    float*  al     = (float*)alloc((size_t)N * 4 * 4);
    float*  ar     = (float*)alloc((size_t)N * 4 * 4);
    int*    rowptr = (int*)alloc((size_t)(N + 1) * 4);
    int*    deg    = (int*)alloc((size_t)N * 4);
    int*    colv   = (int*)alloc((size_t)E * 4);
    unsigned* ebuf = (unsigned*)alloc((size_t)E * 4);
    int*    bwpos  = (int*)alloc((size_t)((N + 255) / 256) * 4);
    int*    parts  = (int*)alloc(256 * 4);
    float*  pooled = (float*)alloc((size_t)G * DIM * 4);
    __bf16* Wb     = (__bf16*)alloc((size_t)3 * 16384 * 2);

    // ---- one-time prep: zero bufs, merged {W pack + degree count}, scans ----
    zero_bufs<<<128, 256, 0, stream>>>(deg, N, pooled, G * DIM);

    const int wtot = 3 * 16384;
    const int wb = (wtot + 255) / 256;
    const int db = (E + 255) / 256;
    prep_pack_deg<<<wb + db, 256, 0, stream>>>(Ws, Wb, wtot, wb, dst, deg, E);

    const int nb = (N + 1023) / 1024;
    scan_blocks<<<nb, 256, 0, stream>>>(deg, rowptr, parts, N);
    scan_partials<<<1, 256, 0, stream>>>(parts, nb, rowptr, N);
    add_offsets<<<nb, 256, 0, stream>>>(rowptr, bwpos, parts, N);

    const int gb = (N + 63) / 64;
    const int cb = (E + 4095) / 4096;
    const int rb = (N + 255) / 256;
    const int ab = 2048;   // persistent aggregate: 8 blocks/CU

    // ---- layer 0 GEMM merged with LDS-classified edge bucketing ----
    gemm0_classify<<<gb + cb, 256, 0, stream>>>(
        x, (const uint4*)Wb, bs, attls, attrs, xlb, al, ar, N, gb,
        src, dst, bwpos, ebuf, E);
    bucket_rank<<<rb, 256, 0, stream>>>(ebuf, rowptr, colv, N);
    gat_aggregate<<<ab, 256, 0, stream>>>(rowptr, colv, al, ar,
        (const unsigned short*)xlb, hA, N);

    // ---- layers 1,2 (bf16 A) ----
    const unsigned short* hin = hA;
    unsigned short* houts[2] = {hB, hA};
    for (int l = 1; l < 3; ++l) {
        unsigned short* hout = houts[l - 1];
        const uint4* Wb4 = (const uint4*)(Wb + (size_t)l * 16384);
        gemm_mfma<true><<<gb, 256, 0, stream>>>(nullptr, hin, Wb4, bs + l*DIM,
            attls + l*DIM, attrs + l*DIM, xlb, al, ar, N);
        gat_aggregate<<<ab, 256, 0, stream>>>(rowptr, colv, al, ar,
            (const unsigned short*)xlb, hout, N);
        hin = hout;
    }

    // ---- pool + projection ----
    pool_nodes_seg<<<(N + POOL_CHUNK - 1) / POOL_CHUNK, 256, 0, stream>>>(hA, batch, pooled, N);
    proj_out<<<(G * 32 + 255) / 256, 256, 0, stream>>>(pooled, projW, projb, (float*)d_out, G);
}

// Round 16
// 256.551 us; speedup vs baseline: 1.1225x; 1.1225x over previous
//
#include <hip/hip_runtime.h>
#include <hip/hip_bf16.h>

#define NHEADS 4
#define DIM 128
#define NEG_SLOPE 0.2f
#define POOL_CHUNK 256

typedef __bf16 bf16x8 __attribute__((ext_vector_type(8)));
typedef float  f32x4  __attribute__((ext_vector_type(4)));

__device__ __forceinline__ float lrelu(float x) { return x > 0.f ? x : NEG_SLOPE * x; }
__device__ __forceinline__ float bf2f(unsigned short u) {
    return __uint_as_float(((unsigned)u) << 16);
}
__device__ __forceinline__ unsigned short f2bf(float f) {
    __bf16 b = (__bf16)f;
    return __builtin_bit_cast(unsigned short, b);
}
__device__ __forceinline__ unsigned pack2bf(float a, float b) {
    return (unsigned)f2bf(a) | ((unsigned)f2bf(b) << 16);
}
__device__ __forceinline__ float4 lrelu4(float4 a, float4 b) {
    return make_float4(lrelu(a.x + b.x), lrelu(a.y + b.y), lrelu(a.z + b.z), lrelu(a.w + b.w));
}
__device__ __forceinline__ float4 redsum4(float4 v) {
#pragma unroll
    for (int off = 32; off >= 1; off >>= 1) {
        v.x += __shfl_xor(v.x, off);
        v.y += __shfl_xor(v.y, off);
        v.z += __shfl_xor(v.z, off);
        v.w += __shfl_xor(v.w, off);
    }
    return v;
}

// ---------------- one-dispatch zero of deg + pooled ----------------
__global__ __launch_bounds__(256) void zero_bufs(
    int* __restrict__ deg, int n, float* __restrict__ pooled, int pn)
{
    int i = blockIdx.x * 256 + threadIdx.x;
    int stride = gridDim.x * 256;
    for (int k = i; k < n; k += stride) deg[k] = 0;
    for (int k = i; k < pn; k += stride) pooled[k] = 0.f;
}

// ---------------- bf16-MFMA GEMM body + fused attention coefficients ----------------
template<bool ABF>
__device__ __forceinline__ void gemm_body(
    const float* __restrict__ inF, const unsigned short* __restrict__ inB,
    const uint4* __restrict__ Wb4, const float* __restrict__ bias,
    const float* __restrict__ attl, const float* __restrict__ attr,
    __bf16* __restrict__ xlb, float* __restrict__ al, float* __restrict__ ar,
    int n, int bid)
{
    const int tid = threadIdx.x;
    const int wid = tid >> 6, l = tid & 63;
    const int rowA = bid * 64 + wid * 16 + (l & 15);
    const int kchunk = (l >> 4) * 8;

    f32x4 acc[8];
#pragma unroll
    for (int g = 0; g < 8; ++g)
#pragma unroll
        for (int r = 0; r < 4; ++r) acc[g][r] = 0.f;

#pragma unroll
    for (int kk = 0; kk < 4; ++kk) {
        bf16x8 afrag;
        if (ABF) {
            uint4 u = make_uint4(0, 0, 0, 0);
            if (rowA < n)
                u = *(const uint4*)(inB + (size_t)rowA * DIM + kk * 32 + kchunk);
            afrag = __builtin_bit_cast(bf16x8, u);
        } else {
            float av[8];
            if (rowA < n) {
                const float* p = inF + (size_t)rowA * DIM + kk * 32 + kchunk;
                float4 x0 = *(const float4*)p;
                float4 x1 = *(const float4*)(p + 4);
                av[0]=x0.x; av[1]=x0.y; av[2]=x0.z; av[3]=x0.w;
                av[4]=x1.x; av[5]=x1.y; av[6]=x1.z; av[7]=x1.w;
            } else {
#pragma unroll
                for (int i = 0; i < 8; ++i) av[i] = 0.f;
            }
#pragma unroll
            for (int i = 0; i < 8; ++i) afrag[i] = (__bf16)av[i];
        }
#pragma unroll
        for (int g = 0; g < 8; ++g) {
            uint4 u = Wb4[(g * 4 + kk) * 64 + l];
            bf16x8 bfrag = __builtin_bit_cast(bf16x8, u);
            acc[g] = __builtin_amdgcn_mfma_f32_16x16x32_bf16(afrag, bfrag, acc[g], 0, 0, 0);
        }
    }

    const int rowbase = bid * 64 + wid * 16 + (l >> 4) * 4;
    float pl[4][4], pr2[4][4];
#pragma unroll
    for (int r = 0; r < 4; ++r)
#pragma unroll
        for (int h = 0; h < 4; ++h) { pl[r][h] = 0.f; pr2[r][h] = 0.f; }

#pragma unroll
    for (int g = 0; g < 8; ++g) {
        int col = g * 16 + (l & 15);
        float bg = bias[col], alg = attl[col], arg = attr[col];
        int h = g >> 1;
#pragma unroll
        for (int r = 0; r < 4; ++r) {
            float v = acc[g][r] + bg;
            int row = rowbase + r;
            if (row < n) xlb[(size_t)row * DIM + col] = (__bf16)v;
            pl[r][h]  = fmaf(v, alg, pl[r][h]);
            pr2[r][h] = fmaf(v, arg, pr2[r][h]);
        }
    }
#pragma unroll
    for (int off = 1; off <= 8; off <<= 1) {
#pragma unroll
        for (int r = 0; r < 4; ++r)
#pragma unroll
            for (int h = 0; h < 4; ++h) {
                pl[r][h]  += __shfl_xor(pl[r][h], off);
                pr2[r][h] += __shfl_xor(pr2[r][h], off);
            }
    }
    if ((l & 15) == 0) {
#pragma unroll
        for (int r = 0; r < 4; ++r) {
            int row = rowbase + r;
            if (row < n) {
#pragma unroll
                for (int h = 0; h < 4; ++h) {
                    al[row * 4 + h] = pl[r][h];
                    ar[row * 4 + h] = pr2[r][h];
                }
            }
        }
    }
}

template<bool ABF>
__global__ __launch_bounds__(256) void gemm_mfma(
    const float* __restrict__ inF, const unsigned short* __restrict__ inB,
    const uint4* __restrict__ Wb4, const float* __restrict__ bias,
    const float* __restrict__ attl, const float* __restrict__ attr,
    __bf16* __restrict__ xlb, float* __restrict__ al, float* __restrict__ ar, int n)
{
    gemm_body<ABF>(inF, inB, Wb4, bias, attl, attr, xlb, al, ar, n, blockIdx.x);
}

// ---- merged: layer-0 GEMM (blocks < gemmBlocks) + LDS-classified edge bucketing ----
__global__ __launch_bounds__(256) void gemm0_classify(
    const float* __restrict__ inF, const uint4* __restrict__ Wb4,
    const float* __restrict__ bias,
    const float* __restrict__ attl, const float* __restrict__ attr,
    __bf16* __restrict__ xlb, float* __restrict__ al, float* __restrict__ ar,
    int n, int gemmBlocks,
    const int* __restrict__ src, const int* __restrict__ dst,
    int* __restrict__ bwpos, unsigned* __restrict__ ebuf, int E)
{
    if ((int)blockIdx.x < gemmBlocks) {
        gemm_body<false>(inF, nullptr, Wb4, bias, attl, attr, xlb, al, ar, n, blockIdx.x);
    } else {
        __shared__ unsigned stage[4096];
        __shared__ unsigned char sid[4096];
        __shared__ int hist[256], lofs[256], wofs[256], gbase[256];
        int t = threadIdx.x;
        int e0 = (blockIdx.x - gemmBlocks) * 4096;
        int cnt = min(4096, E - e0);
        if (cnt <= 0) return;
        hist[t] = 0;
        __syncthreads();
        for (int k = t; k < cnt; k += 256)
            atomicAdd(&hist[dst[e0 + k] >> 8], 1);
        __syncthreads();
        int v = hist[t];
        lofs[t] = v;
        __syncthreads();
        int val = v;
        for (int off = 1; off < 256; off <<= 1) {
            int other = (t >= off) ? lofs[t - off] : 0;
            __syncthreads();
            val += other;
            lofs[t] = val;
            __syncthreads();
        }
        int excl = val - v;
        int gb_ = (v > 0) ? atomicAdd(&bwpos[t], v) : 0;
        lofs[t] = excl; wofs[t] = excl; gbase[t] = gb_;
        __syncthreads();
        for (int k = t; k < cnt; k += 256) {
            int d = dst[e0 + k], s = src[e0 + k];
            int b = d >> 8;
            int slot = atomicAdd(&wofs[b], 1);
            stage[slot] = (unsigned)(s & 0xffff) | ((unsigned)(d & 255) << 16);
            sid[slot] = (unsigned char)b;
        }
        __syncthreads();
        for (int s_ = t; s_ < cnt; s_ += 256) {
            int b = sid[s_];
            ebuf[gbase[b] + (s_ - lofs[b])] = stage[s_];
        }
    }
}

// ---- pass 2: rank within bucket (256 nodes) via LDS counters ----
__global__ __launch_bounds__(256) void bucket_rank(
    const unsigned* __restrict__ ebuf, const int* __restrict__ rowptr,
    int* __restrict__ col, int n)
{
    __shared__ int wp[256];
    int nb0 = blockIdx.x << 8;
    int t = threadIdx.x;
    int nend = min(nb0 + 256, n);
    int base = rowptr[nb0];
    int eend = rowptr[nend];
    if (nb0 + t < nend) wp[t] = rowptr[nb0 + t] - base;
    __syncthreads();
    for (int e = base + t; e < eend; e += 256) {
        unsigned ed = ebuf[e];
        int r = atomicAdd(&wp[(ed >> 16) & 255], 1);
        col[base + r] = (int)(ed & 0xffffu);
    }
}

// ---------------- merged prep: W pack (blocks < wb) + degree count ----------------
__global__ __launch_bounds__(256) void prep_pack_deg(
    const float* __restrict__ Ws, __bf16* __restrict__ Wb, int wtot, int wb,
    const int* __restrict__ dst, int* __restrict__ deg, int E)
{
    if ((int)blockIdx.x < wb) {
        int o = blockIdx.x * 256 + threadIdx.x;
        if (o >= wtot) return;
        int layer = o >> 14;
        int t = o & 16383;
        int j = t & 7, l = (t >> 3) & 63, kk = (t >> 9) & 3, g = t >> 11;
        int col = g * 16 + (l & 15);
        int k = kk * 32 + (l >> 4) * 8 + j;
        Wb[o] = (__bf16)Ws[(size_t)layer * 16384 + col * 128 + k];
    } else {
        int e = (blockIdx.x - wb) * 256 + threadIdx.x;
        if (e < E) atomicAdd(&deg[dst[e]], 1);
    }
}

__global__ __launch_bounds__(256) void scan_blocks(
    const int* __restrict__ deg, int* __restrict__ rowptr,
    int* __restrict__ partials, int n)
{
    __shared__ int tot[256];
    int t = threadIdx.x;
    int base = blockIdx.x * 1024 + t * 4;
    int v[4];
#pragma unroll
    for (int j = 0; j < 4; ++j) v[j] = (base + j < n) ? deg[base + j] : 0;
    int p1 = v[0], p2 = p1 + v[1], p3 = p2 + v[2], sum4 = p3 + v[3];
    tot[t] = sum4;
    __syncthreads();
    int val = sum4;
    for (int off = 1; off < 256; off <<= 1) {
        int other = (t >= off) ? tot[t - off] : 0;
        __syncthreads();
        val += other;
        tot[t] = val;
        __syncthreads();
    }
    int excl = val - sum4;
    if (base < n)     rowptr[base]     = excl;
    if (base+1 < n)   rowptr[base+1]   = excl + p1;
    if (base+2 < n)   rowptr[base+2]   = excl + p2;
    if (base+3 < n)   rowptr[base+3]   = excl + p3;
    if (t == 255) partials[blockIdx.x] = val;
}

__global__ __launch_bounds__(256) void scan_partials(
    int* __restrict__ partials, int nb, int* __restrict__ rowptr, int n)
{
    __shared__ int tot[256];
    int t = threadIdx.x;
    int v = (t < nb) ? partials[t] : 0;
    tot[t] = v;
    __syncthreads();
    int val = v;
    for (int off = 1; off < 256; off <<= 1) {
        int other = (t >= off) ? tot[t - off] : 0;
        __syncthreads();
        val += other;
        tot[t] = val;
        __syncthreads();
    }
    if (t < nb) partials[t] = val - v;
    if (t == 255) rowptr[n] = val;
}

// also seeds bwpos[b] = rowptr[b*256]
__global__ __launch_bounds__(256) void add_offsets(
    int* __restrict__ rowptr, int* __restrict__ bwpos,
    const int* __restrict__ partials, int n)
{
    int base = blockIdx.x * 1024 + threadIdx.x * 4;
    int off = partials[blockIdx.x];
#pragma unroll
    for (int j = 0; j < 4; ++j) {
        int i = base + j;
        if (i < n) {
            int r = rowptr[i] + off;
            rowptr[i] = r;
            if ((i & 255) == 0) bwpos[i >> 8] = r;
        }
    }
}

// ---- accumulate one edge (uint4 = 8 bf16 ch) into a pair of f32x4 ----
__device__ __forceinline__ void acc_edge(
    uint4 v, float w, f32x4& lo, f32x4& hi)
{
    lo[0] = fmaf(w, __uint_as_float(v.x << 16), lo[0]);
    lo[1] = fmaf(w, __uint_as_float(v.x & 0xffff0000u), lo[1]);
    lo[2] = fmaf(w, __uint_as_float(v.y << 16), lo[2]);
    lo[3] = fmaf(w, __uint_as_float(v.y & 0xffff0000u), lo[3]);
    hi[0] = fmaf(w, __uint_as_float(v.z << 16), hi[0]);
    hi[1] = fmaf(w, __uint_as_float(v.z & 0xffff0000u), hi[1]);
    hi[2] = fmaf(w, __uint_as_float(v.w << 16), hi[2]);
    hi[3] = fmaf(w, __uint_as_float(v.w & 0xffff0000u), hi[3]);
}

// chunk of <=64 staged edges; 4 edges/wave-inst (16 lanes x 8ch, uint4 loads),
// 2 unroll groups -> 8 edges in flight (R11 proven form — wider ILP costs
// occupancy R6/R12; persistent grid hurts locality R14). Tail: FULL guarded loop.
__device__ __forceinline__ void agg_chunk4w(
    const int* __restrict__ slds, const float* __restrict__ wl,
    int cn, int eg, const unsigned short* __restrict__ xp,
    f32x4& A0, f32x4& A1, f32x4& B0, f32x4& B1)
{
    int i = 0;
    for (; i + 8 <= cn; i += 8) {
        int e0 = i + eg, e1 = i + 4 + eg;
        int s0 = slds[e0], s1 = slds[e1];
        float w0 = wl[e0*4], w1 = wl[e1*4];
        uint4 v0 = *(const uint4*)(xp + (size_t)s0 * DIM);
        uint4 v1 = *(const uint4*)(xp + (size_t)s1 * DIM);
        acc_edge(v0, w0, A0, A1);
        acc_edge(v1, w1, B0, B1);
    }
    for (; i < cn; i += 4) {
        int e = i + eg;
        if (e < cn) {
            int s = slds[e];
            float w = wl[e*4];
            uint4 v = *(const uint4*)(xp + (size_t)s * DIM);
            acc_edge(v, w, A0, A1);
        }
    }
}

// ---------------- fused per-node softmax + aggregate (bf16 gather) ----------
__global__ __launch_bounds__(256) void gat_aggregate(
    const int* __restrict__ rowptr, const int* __restrict__ col,
    const float* __restrict__ al, const float* __restrict__ ar,
    const unsigned short* __restrict__ xlb, unsigned short* __restrict__ outb, int n)
{
    __shared__ float4 wlds[4][64];
    __shared__ int    slds[4][64];
    int wid = threadIdx.x >> 6;
    int node = blockIdx.x * 4 + wid;
    if (node >= n) return;
    int lane = threadIdx.x & 63;
    int eg = lane >> 4, c16 = lane & 15;
    int h = c16 >> 2;
    int r0 = rowptr[node], r1 = rowptr[node + 1];
    int deg = r1 - r0;
    unsigned short* po = outb + (size_t)node * DIM + c16 * 8;
    if (deg == 0) {
        if (eg == 0) *(uint4*)po = make_uint4(0, 0, 0, 0);
        return;
    }

    float4 arv = *(const float4*)(ar + (size_t)node * 4);
    const float* wl = (const float*)&wlds[wid][0] + h;
    const unsigned short* xp = xlb + c16 * 8;
    f32x4 A0 = {0,0,0,0}, A1 = {0,0,0,0}, B0 = {0,0,0,0}, B1 = {0,0,0,0};
    float4 inv4;

    if (deg <= 64) {
        float4 p4 = make_float4(0.f, 0.f, 0.f, 0.f);
        int s = 0;
        if (lane < deg) {
            s = col[r0 + lane];
            float4 a = *(const float4*)(al + (size_t)s * 4);
            float4 l4 = lrelu4(arv, a);
            p4.x = __expf(l4.x); p4.y = __expf(l4.y);
            p4.z = __expf(l4.z); p4.w = __expf(l4.w);
        }
        float4 s4 = redsum4(p4);
        inv4 = make_float4(1.f/(s4.x+1e-16f), 1.f/(s4.y+1e-16f),
                           1.f/(s4.z+1e-16f), 1.f/(s4.w+1e-16f));
        if (lane < deg) { wlds[wid][lane] = p4; slds[wid][lane] = s; }
        __asm__ volatile("s_waitcnt lgkmcnt(0)" ::: "memory");
        __builtin_amdgcn_sched_barrier(0);
        agg_chunk4w(&slds[wid][0], wl, deg, eg, xp, A0, A1, B0, B1);
    } else {
        float4 s4 = make_float4(0.f, 0.f, 0.f, 0.f);
        for (int i = lane; i < deg; i += 64) {
            int s = col[r0 + i];
            float4 a = *(const float4*)(al + (size_t)s * 4);
            float4 t = lrelu4(arv, a);
            s4.x += __expf(t.x); s4.y += __expf(t.y);
            s4.z += __expf(t.z); s4.w += __expf(t.w);
        }
        s4 = redsum4(s4);
        inv4 = make_float4(1.f/(s4.x+1e-16f), 1.f/(s4.y+1e-16f),
                           1.f/(s4.z+1e-16f), 1.f/(s4.w+1e-16f));
        for (int c0 = 0; c0 < deg; c0 += 64) {
            int cn = min(64, deg - c0);
            if (lane < cn) {
                int s = col[r0 + c0 + lane];
                float4 a = *(const float4*)(al + (size_t)s * 4);
                float4 t = lrelu4(arv, a);
                float4 p;
                p.x = __expf(t.x); p.y = __expf(t.y);
                p.z = __expf(t.z); p.w = __expf(t.w);
                wlds[wid][lane] = p; slds[wid][lane] = s;
            }
            __asm__ volatile("s_waitcnt lgkmcnt(0)" ::: "memory");
            __builtin_amdgcn_sched_barrier(0);
            agg_chunk4w(&slds[wid][0], wl, cn, eg, xp, A0, A1, B0, B1);
            __asm__ volatile("s_waitcnt lgkmcnt(0)" ::: "memory");
            __builtin_amdgcn_sched_barrier(0);
        }
    }
    float invh = (h == 0) ? inv4.x : (h == 1) ? inv4.y : (h == 2) ? inv4.z : inv4.w;
#pragma unroll
    for (int j = 0; j < 4; ++j) {
        A0[j] += B0[j];
        A1[j] += B1[j];
        A0[j] += __shfl_xor(A0[j], 16); A0[j] += __shfl_xor(A0[j], 32);
        A1[j] += __shfl_xor(A1[j], 16); A1[j] += __shfl_xor(A1[j], 32);
    }
    if (eg == 0) {
        uint4 o4;
        o4.x = pack2bf(fmaxf(A0[0]*invh, 0.f), fmaxf(A0[1]*invh, 0.f));
        o4.y = pack2bf(fmaxf(A0[2]*invh, 0.f), fmaxf(A0[3]*invh, 0.f));
        o4.z = pack2bf(fmaxf(A1[0]*invh, 0.f), fmaxf(A1[1]*invh, 0.f));
        o4.w = pack2bf(fmaxf(A1[2]*invh, 0.f), fmaxf(A1[3]*invh, 0.f));
        *(uint4*)po = o4;
    }
}

// ---------------- graph pooling: segmented (batch sorted); h relu'd bf16 ----
__global__ __launch_bounds__(256) void pool_nodes_seg(
    const unsigned short* __restrict__ h, const int* __restrict__ batch,
    float* __restrict__ pooled, int n)
{
    int wid = threadIdx.x >> 6;
    int lane = threadIdx.x & 63;
    int start = blockIdx.x * POOL_CHUNK;
    int end = min(start + POOL_CHUNK, n);
    float a0 = 0.f, a1 = 0.f;
    int curg = -1;
    for (int node = start + wid; node < end; node += 4) {
        int g = batch[node];
        if (g != curg) {
            if (curg >= 0) {
                unsafeAtomicAdd(pooled + (size_t)curg * DIM + lane*2,     a0);
                unsafeAtomicAdd(pooled + (size_t)curg * DIM + lane*2 + 1, a1);
            }
            curg = g; a0 = 0.f; a1 = 0.f;
        }
        ushort2 v = *(const ushort2*)(h + (size_t)node * DIM + lane * 2);
        a0 += bf2f(v.x);
        a1 += bf2f(v.y);
    }
    if (curg >= 0) {
        unsafeAtomicAdd(pooled + (size_t)curg * DIM + lane*2,     a0);
        unsafeAtomicAdd(pooled + (size_t)curg * DIM + lane*2 + 1, a1);
    }
}

// ---------------- final projection ----------------
__global__ __launch_bounds__(256) void proj_out(
    const float* __restrict__ pooled, const float* __restrict__ W,
    const float* __restrict__ b, float* __restrict__ out, int G)
{
    int idx = blockIdx.x * blockDim.x + threadIdx.x;
    if (idx >= G * 32) return;
    int g = idx >> 5, j = idx & 31;
    const float* pr = pooled + (size_t)g * DIM;
    const float* wr = W + (size_t)j * DIM;
    float acc = 0.f;
#pragma unroll
    for (int k = 0; k < DIM; ++k) acc = fmaf(pr[k], wr[k], acc);
    out[idx] = acc + b[j];
}

extern "C" void kernel_launch(void* const* d_in, const int* in_sizes, int n_in,
                              void* d_out, int out_size, void* d_ws, size_t ws_size,
                              hipStream_t stream)
{
    const float* x      = (const float*)d_in[0];
    const int*   eidx   = (const int*)d_in[1];
    const int*   batch  = (const int*)d_in[2];
    const float* Ws     = (const float*)d_in[3];
    const float* bs     = (const float*)d_in[4];
    const float* attls  = (const float*)d_in[5];
    const float* attrs  = (const float*)d_in[6];
    const float* projW  = (const float*)d_in[7];
    const float* projb  = (const float*)d_in[8];

    const int N = in_sizes[0] / DIM;
    const int E = in_sizes[1] / 2;
    const int G = out_size / 32;
    const int* src = eidx;
    const int* dst = eidx + E;

    char* ws = (char*)d_ws;
    size_t o = 0;
    auto alloc = [&](size_t bytes) { char* p = ws + o; o += (bytes + 255) & ~255ull; return p; };
    unsigned short* hA  = (unsigned short*)alloc((size_t)N * DIM * 2);
    unsigned short* hB  = (unsigned short*)alloc((size_t)N * DIM * 2);
    __bf16* xlb    = (__bf16*)alloc((size_t)N * DIM * 2);
    float*  al     = (float*)alloc((size_t)N * 4 * 4);
    float*  ar     = (float*)alloc((size_t)N * 4 * 4);
    int*    rowptr = (int*)alloc((size_t)(N + 1) * 4);
    int*    deg    = (int*)alloc((size_t)N * 4);
    int*    colv   = (int*)alloc((size_t)E * 4);
    unsigned* ebuf = (unsigned*)alloc((size_t)E * 4);
    int*    bwpos  = (int*)alloc((size_t)((N + 255) / 256) * 4);
    int*    parts  = (int*)alloc(256 * 4);
    float*  pooled = (float*)alloc((size_t)G * DIM * 4);
    __bf16* Wb     = (__bf16*)alloc((size_t)3 * 16384 * 2);

    // ---- one-time prep: zero bufs, merged {W pack + degree count}, scans ----
    zero_bufs<<<128, 256, 0, stream>>>(deg, N, pooled, G * DIM);

    const int wtot = 3 * 16384;
    const int wb = (wtot + 255) / 256;
    const int db = (E + 255) / 256;
    prep_pack_deg<<<wb + db, 256, 0, stream>>>(Ws, Wb, wtot, wb, dst, deg, E);

    const int nb = (N + 1023) / 1024;
    scan_blocks<<<nb, 256, 0, stream>>>(deg, rowptr, parts, N);
    scan_partials<<<1, 256, 0, stream>>>(parts, nb, rowptr, N);
    add_offsets<<<nb, 256, 0, stream>>>(rowptr, bwpos, parts, N);

    const int gb = (N + 63) / 64;
    const int cb = (E + 4095) / 4096;
    const int rb = (N + 255) / 256;

    // ---- layer 0 GEMM merged with LDS-classified edge bucketing ----
    gemm0_classify<<<gb + cb, 256, 0, stream>>>(
        x, (const uint4*)Wb, bs, attls, attrs, xlb, al, ar, N, gb,
        src, dst, bwpos, ebuf, E);
    bucket_rank<<<rb, 256, 0, stream>>>(ebuf, rowptr, colv, N);
    gat_aggregate<<<(N + 3) / 4, 256, 0, stream>>>(rowptr, colv, al, ar,
        (const unsigned short*)xlb, hA, N);

    // ---- layers 1,2 (bf16 A) ----
    const unsigned short* hin = hA;
    unsigned short* houts[2] = {hB, hA};
    for (int l = 1; l < 3; ++l) {
        unsigned short* hout = houts[l - 1];
        const uint4* Wb4 = (const uint4*)(Wb + (size_t)l * 16384);
        gemm_mfma<true><<<gb, 256, 0, stream>>>(nullptr, hin, Wb4, bs + l*DIM,
            attls + l*DIM, attrs + l*DIM, xlb, al, ar, N);
        gat_aggregate<<<(N + 3) / 4, 256, 0, stream>>>(rowptr, colv, al, ar,
            (const unsigned short*)xlb, hout, N);
        hin = hout;
    }

    // ---- pool + projection ----
    pool_nodes_seg<<<(N + POOL_CHUNK - 1) / POOL_CHUNK, 256, 0, stream>>>(hA, batch, pooled, N);
    proj_out<<<(G * 32 + 255) / 256, 256, 0, stream>>>(pooled, projW, projb, (float*)d_out, G);
}